// Round 1
// baseline (260.001 us; speedup 1.0000x reference)
//
#include <hip/hip_runtime.h>

// Problem: 8 stacked 3x3 same-pad convs (1 channel) on independent 3x3 images.
// Collapses to a single affine map out = A*x + c with A (9x9), c (9).
// Kernel 1 composes A,c from weights/biases into d_ws (re-done every launch:
// d_ws is re-poisoned by the harness). Kernel 2 is a pure-BW affine apply.

constexpr int ROWS = 256;                 // rows per block
constexpr int F4_PER_BLOCK = ROWS * 9 / 4; // 576 float4 per block (9216 B)

// ---------------- Kernel 1: compose the affine map --------------------------
__global__ void compose_affine(const float* __restrict__ w,   // [8,3,3] flat
                               const float* __restrict__ b,   // [8]
                               float* __restrict__ aff)       // [90] out: A(81) then c(9)
{
    __shared__ float A[2][81];
    __shared__ float C[2][9];
    const int t = threadIdx.x;

    if (t < 81) A[0][t] = (t / 9 == t % 9) ? 1.0f : 0.0f;
    if (t < 9)  C[0][t] = 0.0f;
    __syncthreads();

    int cur = 0;
    for (int d = 0; d < 8; ++d) {
        if (t < 81) {
            const int i = t / 9, j = t % 9;       // A element (i,j)
            const int r = i / 3, cc = i % 3;      // output pixel of this layer
            float acc = 0.0f;
            float accc = (j == 0) ? b[d] : 0.0f;
            #pragma unroll
            for (int k = 0; k < 9; ++k) {
                const int rr = k / 3, kc = k % 3; // input pixel
                const int dr = rr - r + 1, dc = kc - cc + 1;
                float m = 0.0f;
                if (dr >= 0 && dr < 3 && dc >= 0 && dc < 3)
                    m = w[d * 9 + dr * 3 + dc];   // cross-correlation (torch/jax conv)
                acc = fmaf(m, A[cur][k * 9 + j], acc);
                if (j == 0) accc = fmaf(m, C[cur][k], accc);
            }
            A[1 - cur][t] = acc;
            if (j == 0) C[1 - cur][i] = accc;
        }
        __syncthreads();
        cur = 1 - cur;
    }
    if (t < 81) aff[t] = A[cur][t];
    if (t < 9)  aff[81 + t] = C[cur][t];
}

// ---------------- Kernel 2: apply out = A*x + c (BW-bound) ------------------
__global__ __launch_bounds__(256) void apply_affine(
    const float* __restrict__ x,
    const float* __restrict__ aff,
    float* __restrict__ out,
    long long n_f4,          // total float4 count = N*9/4
    long long n_rows)
{
    __shared__ float tile[ROWS * 9];  // 9216 B
    const int t = threadIdx.x;
    const long long base_f4 = (long long)blockIdx.x * F4_PER_BLOCK;

    // Stage global -> LDS as float4 (fully coalesced, 16B/lane).
    const float4* __restrict__ in4 = (const float4*)x;
    float4* t4 = (float4*)tile;
    #pragma unroll
    for (int k = 0; k < 3; ++k) {
        const int idx = t + k * 256;
        if (idx < F4_PER_BLOCK) {
            const long long g = base_f4 + idx;
            if (g < n_f4) t4[idx] = in4[g];
        }
    }
    __syncthreads();

    const long long row = (long long)blockIdx.x * ROWS + t;
    if (row < n_rows) {
        // Row read: stride-9 floats -> 9 coprime with 32 banks: conflict-free
        // per 32 lanes, 2-way across wave64 (free).
        float xv[9];
        #pragma unroll
        for (int j = 0; j < 9; ++j) xv[j] = tile[t * 9 + j];

        // aff is wave-uniform with literal offsets -> scalar (s_load) operands.
        float y[9];
        #pragma unroll
        for (int i = 0; i < 9; ++i) y[i] = aff[81 + i];
        #pragma unroll
        for (int k = 0; k < 9; ++k) {
            #pragma unroll
            for (int i = 0; i < 9; ++i)
                y[i] = fmaf(aff[i * 9 + k], xv[k], y[i]);
        }

        // Write own region back (only this thread touches tile[t*9 .. t*9+8]
        // between the two barriers -> no extra barrier needed).
        #pragma unroll
        for (int j = 0; j < 9; ++j) tile[t * 9 + j] = y[j];
    }
    __syncthreads();

    float4* __restrict__ out4 = (float4*)out;
    #pragma unroll
    for (int k = 0; k < 3; ++k) {
        const int idx = t + k * 256;
        if (idx < F4_PER_BLOCK) {
            const long long g = base_f4 + idx;
            if (g < n_f4) out4[g] = t4[idx];
        }
    }
}

extern "C" void kernel_launch(void* const* d_in, const int* in_sizes, int n_in,
                              void* d_out, int out_size, void* d_ws, size_t ws_size,
                              hipStream_t stream) {
    const float* x = (const float*)d_in[0];   // [N,9] fp32
    const float* w = (const float*)d_in[1];   // [8,1,1,3,3] fp32
    const float* b = (const float*)d_in[2];   // [8] fp32
    float* out = (float*)d_out;
    float* aff = (float*)d_ws;                // 90 floats

    const long long n_elems = (long long)in_sizes[0];   // 36,000,000
    const long long n_rows  = n_elems / 9;              // 4,000,000
    const long long n_f4    = n_elems / 4;              // 9,000,000

    compose_affine<<<1, 128, 0, stream>>>(w, b, aff);

    const long long blocks = (n_rows + ROWS - 1) / ROWS; // 15625
    apply_affine<<<dim3((unsigned)blocks), dim3(256), 0, stream>>>(
        x, aff, out, n_f4, n_rows);
}